// Round 2
// baseline (622.800 us; speedup 1.0000x reference)
//
#include <hip/hip_runtime.h>
#include <hip/hip_bf16.h>
#include <math.h>

#define B_   4
#define S_   2048
#define D_   1024
#define H_   16
#define HD_  64
#define DFF_ 4096
#define M_   (B_*S_)   // 8192 rows

typedef __bf16 bf16x8 __attribute__((ext_vector_type(8)));
typedef __bf16 bf16x4 __attribute__((ext_vector_type(4)));
typedef float  floatx4 __attribute__((ext_vector_type(4)));

__device__ __forceinline__ float  b2f(__bf16 v) { return (float)v; }
__device__ __forceinline__ __bf16 f2b(float v)  { return (__bf16)v; }

// async global->LDS, 16 bytes per lane. LDS dests MUST be base + lane*16.
__device__ __forceinline__ void async_ld16(const void* g, void* l) {
    __builtin_amdgcn_global_load_lds(
        (const __attribute__((address_space(1))) unsigned int*)g,
        (__attribute__((address_space(3))) unsigned int*)l, 16, 0, 0);
}

// ---------------------------------------------------------------------------
// Transpose + convert + scale: out[c*R + r] = bf16(in[r*C + c] * scale).
// ---------------------------------------------------------------------------
__global__ void transpose_conv_kernel(const float* __restrict__ in,
                                      __bf16* __restrict__ out, int R, int C,
                                      float scale)
{
    __shared__ float t[32][33];
    int c0 = blockIdx.x * 32, r0 = blockIdx.y * 32;
    int tx = threadIdx.x, ty = threadIdx.y;
    for (int i = ty; i < 32; i += 8)
        t[i][tx] = in[(long)(r0 + i) * C + c0 + tx];
    __syncthreads();
    for (int i = ty; i < 32; i += 8)
        out[(long)(c0 + i) * R + r0 + tx] = f2b(t[tx][i] * scale);
}

// bf16 V -> global transposed vtg[b][h][d][s]  (once; frees attn inner loop)
__global__ void vt_transpose_kernel(const __bf16* __restrict__ qkv,
                                    __bf16* __restrict__ vtg)
{
    __shared__ __bf16 t[32][34];
    int b  = blockIdx.z;
    int h  = blockIdx.y >> 1;
    int d0 = (blockIdx.y & 1) * 32;
    int s0 = blockIdx.x * 32;
    int tx = threadIdx.x, ty = threadIdx.y;
    for (int i = ty; i < 32; i += 8)
        t[i][tx] = qkv[(long)(b * S_ + s0 + i) * 3072 + 2048 + h * 64 + d0 + tx];
    __syncthreads();
    for (int i = ty; i < 32; i += 8)
        vtg[((long)(b * H_ + h) * 64 + d0 + i) * S_ + s0 + tx] = t[tx][i];
}

// fp32 -> bf16 elementwise (n multiple of 8)
__global__ void f2b_kernel(const float* __restrict__ in, __bf16* __restrict__ out,
                           long n)
{
    long i = ((long)blockIdx.x * 256 + threadIdx.x) * 8;
    if (i >= n) return;
    float4 a = *(const float4*)&in[i];
    float4 c = *(const float4*)&in[i + 4];
    union { __bf16 h[8]; uint4 u; } p;
    p.h[0] = f2b(a.x); p.h[1] = f2b(a.y); p.h[2] = f2b(a.z); p.h[3] = f2b(a.w);
    p.h[4] = f2b(c.x); p.h[5] = f2b(c.y); p.h[6] = f2b(c.z); p.h[7] = f2b(c.w);
    *(uint4*)&out[i] = p.u;
}

// concat q/k/v biases; q part scaled by 0.125 (score scale folded into Wq,bq)
__global__ void bias_concat_kernel(const float* __restrict__ bq,
                                   const float* __restrict__ bk,
                                   const float* __restrict__ bv,
                                   float* __restrict__ dst)
{
    int i = blockIdx.x * 256 + threadIdx.x;
    if (i >= 3 * D_) return;
    float v = (i < D_) ? bq[i] * 0.125f
            : (i < 2 * D_) ? bk[i - D_] : bv[i - 2 * D_];
    dst[i] = v;
}

// ---------------------------------------------------------------------------
// bf16 MFMA GEMM 128x128 (m97 structure + XOR bank-swizzle): C = A * Bt^T
//   MODE 0: Cb = bf16(acc + bias)
//   MODE 1: Cf = acc + bias + resid       (fp32, feeds LayerNorm)
//   MODE 2: Cb = bf16(gelu(acc + bias))
// Used for N=1024 GEMMs (grid would be too small for the 256^2 kernel).
// ---------------------------------------------------------------------------
template<int MODE>
__global__ __launch_bounds__(256, 2)
void gemm_kernel(const __bf16* __restrict__ A, const __bf16* __restrict__ Bt,
                 const float* __restrict__ bias, const float* __restrict__ resid,
                 float* __restrict__ Cf, __bf16* __restrict__ Cb,
                 int M, int N, int K)
{
    __shared__ __bf16 sA[128 * 64];
    __shared__ __bf16 sB[128 * 64];

    const int tid  = threadIdx.x;
    const int lane = tid & 63;
    const int wave = tid >> 6;
    const int wm   = (wave >> 1) * 64;
    const int wn   = (wave & 1) * 64;
    const long bm  = (long)blockIdx.y * 128;
    const long bn  = (long)blockIdx.x * 128;

    floatx4 acc[4][4];
#pragma unroll
    for (int i = 0; i < 4; ++i)
#pragma unroll
        for (int j = 0; j < 4; ++j)
#pragma unroll
            for (int r = 0; r < 4; ++r) acc[i][j][r] = 0.0f;

    const int mrow = lane & 15;
    const int quad = lane >> 4;
    const int koff0 = ((0 * 4 + quad) ^ (mrow & 7)) * 8;
    const int koff1 = ((1 * 4 + quad) ^ (mrow & 7)) * 8;

    for (int k0 = 0; k0 < K; k0 += 64) {
        __syncthreads();
#pragma unroll
        for (int t = 0; t < 4; ++t) {
            int ci  = tid + t * 256;
            int row = ci >> 3;
            int col = ((ci & 7) ^ (row & 7)) << 3;   // XOR swizzle on global
            async_ld16(A  + (bm + row) * (long)K + k0 + col, &sA[ci * 8]);
            async_ld16(Bt + (bn + row) * (long)K + k0 + col, &sB[ci * 8]);
        }
        __syncthreads();

#pragma unroll
        for (int s = 0; s < 2; ++s) {
            const int ko = s ? koff1 : koff0;
            bf16x8 a[4], b[4];
#pragma unroll
            for (int i = 0; i < 4; ++i)
                a[i] = *(const bf16x8*)&sA[(wm + i * 16 + mrow) * 64 + ko];
#pragma unroll
            for (int j = 0; j < 4; ++j)
                b[j] = *(const bf16x8*)&sB[(wn + j * 16 + mrow) * 64 + ko];
#pragma unroll
            for (int i = 0; i < 4; ++i)
#pragma unroll
                for (int j = 0; j < 4; ++j)
                    acc[i][j] = __builtin_amdgcn_mfma_f32_16x16x32_bf16(
                        a[i], b[j], acc[i][j], 0, 0, 0);
        }
    }

    // D: row = quad*4 + reg, col = lane&15   [verified m89/m91]
    const int rq = quad * 4;
    const int cn = lane & 15;
#pragma unroll
    for (int i = 0; i < 4; ++i) {
#pragma unroll
        for (int j = 0; j < 4; ++j) {
            long col = bn + wn + j * 16 + cn;
            float bv = bias[col];
#pragma unroll
            for (int r = 0; r < 4; ++r) {
                long row = bm + wm + i * 16 + rq + r;
                float v = acc[i][j][r] + bv;
                if (MODE == 0) {
                    Cb[row * N + col] = f2b(v);
                } else if (MODE == 1) {
                    Cf[row * N + col] = v + resid[row * N + col];
                } else {
                    float g = 0.5f * v * (1.0f + erff(v * 0.70710678118654752f));
                    Cb[row * N + col] = f2b(g);
                }
            }
        }
    }
}

// ---------------------------------------------------------------------------
// bf16 MFMA GEMM 256x256, 8-wave, 4-phase-per-K-tile pipelined schedule
// (T3+T4+T5 port of the 256^2 8-phase template). C = A[M,K] * Bt[N,K]^T.
// Requires M%256==0, N%256==0, K%64==0, K>=192, grid = (N/256, M/256).
//
// Wave w: row-group g=w>>2, col-group c=w&3. Wave output rows interleave the
// two A-halves (rows g*64+qi*128+i*16), cols interleave the two B-halves
// (cols c*32+qj*128+j*16) -> every phase (qi,qj) uses exactly one A-half and
// one B-half, enabling half-granular prefetch with counted vmcnt.
//
// Per K-tile t (4 phases, quadrants (0,0),(0,1),(1,1),(1,0)); stages into the
// dbuf: ph0: A1(t+1), ph1: B0(t+1), ph2: A0(t+2), ph3: B1(t+2).
// Single vmcnt(4) per tile at ph3 (before its barrier): leaves the newest 2
// half-tiles (A0(t+2),B1(t+2)) in flight, guarantees tile t+1 landed.
// Ledger: every LDS region's overwrite is issued >=1 barrier after its last
// read (A0 read ph0/ph1, overwritten ph2; B1 read ph1/ph2, overwritten ph3;
// A1/B0 of buf^1 last read end of t-1, overwritten ph0/ph1 of t).
// ---------------------------------------------------------------------------
template<int MODE>
__global__ __launch_bounds__(512, 2)
void gemm256_kernel(const __bf16* __restrict__ A, const __bf16* __restrict__ Bt,
                    const float* __restrict__ bias, const float* __restrict__ resid,
                    float* __restrict__ Cf, __bf16* __restrict__ Cb,
                    int M, int N, int K)
{
    __shared__ __bf16 sA[2][256 * 64];
    __shared__ __bf16 sB[2][256 * 64];

    // XCD-aware bijective block swizzle (m204 form; exact when nwg%8==0)
    const int nbx = gridDim.x;
    const int nwg = nbx * gridDim.y;
    const int orig = blockIdx.y * nbx + blockIdx.x;
    const int q8 = nwg >> 3, r8 = nwg & 7, xcd = orig & 7, off = orig >> 3;
    const int wg = (xcd < r8 ? xcd * (q8 + 1) : r8 * (q8 + 1) + (xcd - r8) * q8) + off;
    const long bm = (long)(wg / nbx) * 256;
    const long bn = (long)(wg % nbx) * 256;

    const int tid  = threadIdx.x;
    const int lane = tid & 63;
    const int wave = tid >> 6;
    const int g    = wave >> 2;        // A row-group (0..1)
    const int c    = wave & 3;         // B col-group (0..3)
    const int cn   = lane & 15;
    const int quad = lane >> 4;
    const int rq   = quad * 4;

    floatx4 acc[2][2][4][2];           // [qi][qj][i][j]
#pragma unroll
    for (int qi = 0; qi < 2; ++qi)
#pragma unroll
    for (int qj = 0; qj < 2; ++qj)
#pragma unroll
    for (int i = 0; i < 4; ++i)
#pragma unroll
    for (int j = 0; j < 2; ++j)
#pragma unroll
        for (int r = 0; r < 4; ++r) acc[qi][qj][i][j][r] = 0.0f;

    const int NT = K >> 6;

    // stage one half-tile (128 rows x 64 cols bf16, 2 async_ld16/thread)
    auto STAGE = [&](int pb, int isB, int half, int t) {
        const __bf16* src = isB ? Bt : A;
        const long    base = isB ? bn : bm;
        __bf16*       dst  = isB ? &sB[pb][0] : &sA[pb][0];
        const int k0 = t << 6;
#pragma unroll
        for (int tt = 0; tt < 2; ++tt) {
            int ci  = tid + tt * 512;
            int row = (ci >> 3) + half * 128;
            int col = ((ci & 7) ^ (row & 7)) << 3;   // inverse swizzle on src
            async_ld16(src + (base + row) * (long)K + k0 + col,
                       dst + half * 8192 + ci * 8);
        }
    };
    auto LDA = [&](int pb, int qi, bf16x8 (&a)[2][4]) {
#pragma unroll
        for (int i = 0; i < 4; ++i) {
            int rr = g * 64 + qi * 128 + i * 16 + cn;
#pragma unroll
            for (int s = 0; s < 2; ++s) {
                int ko = ((s * 4 + quad) ^ (rr & 7)) << 3;
                a[s][i] = *(const bf16x8*)&sA[pb][rr * 64 + ko];
            }
        }
    };
    auto LDB = [&](int pb, int qj, bf16x8 (&b)[2][2]) {
#pragma unroll
        for (int j = 0; j < 2; ++j) {
            int rr = c * 32 + qj * 128 + j * 16 + cn;
#pragma unroll
            for (int s = 0; s < 2; ++s) {
                int ko = ((s * 4 + quad) ^ (rr & 7)) << 3;
                b[s][j] = *(const bf16x8*)&sB[pb][rr * 64 + ko];
            }
        }
    };
    auto MM = [&](bf16x8 (&a)[2][4], bf16x8 (&b)[2][2], floatx4 (&ac)[4][2]) {
#pragma unroll
        for (int s = 0; s < 2; ++s)
#pragma unroll
        for (int i = 0; i < 4; ++i)
#pragma unroll
        for (int j = 0; j < 2; ++j)
            ac[i][j] = __builtin_amdgcn_mfma_f32_16x16x32_bf16(
                a[s][i], b[s][j], ac[i][j], 0, 0, 0);
    };

    // ---- prologue: tile0 {A0,B0,B1,A1} + tile1 {A0,B1} ----
    STAGE(0, 0, 0, 0); STAGE(0, 1, 0, 0); STAGE(0, 1, 1, 0); STAGE(0, 0, 1, 0);
    STAGE(1, 0, 0, 1); STAGE(1, 1, 1, 1);
    asm volatile("s_waitcnt vmcnt(4)" ::: "memory");   // tile0 landed
    __builtin_amdgcn_s_barrier();
    __builtin_amdgcn_sched_barrier(0);

    bf16x8 a[2][4], b[2][2];
    for (int t = 0; t < NT; ++t) {
        const int pb = t & 1;
        // ---------- phase 0: (qi=0, qj=0) ----------
        LDA(pb, 0, a); LDB(pb, 0, b);                  // 12 ds_read_b128
        if (t + 1 < NT) STAGE(pb ^ 1, 0, 1, t + 1);    // A1(t+1)
        asm volatile("s_waitcnt lgkmcnt(8)" ::: "memory");
        __builtin_amdgcn_s_barrier();
        asm volatile("s_waitcnt lgkmcnt(0)" ::: "memory");
        __builtin_amdgcn_sched_barrier(0);
        __builtin_amdgcn_s_setprio(1);
        MM(a, b, acc[0][0]);
        __builtin_amdgcn_s_setprio(0);
        __builtin_amdgcn_s_barrier();
        __builtin_amdgcn_sched_barrier(0);
        // ---------- phase 1: (0, 1) ----------
        LDB(pb, 1, b);                                 // 4 ds_read_b128
        if (t + 1 < NT) STAGE(pb ^ 1, 1, 0, t + 1);    // B0(t+1)
        __builtin_amdgcn_s_barrier();
        asm volatile("s_waitcnt lgkmcnt(0)" ::: "memory");
        __builtin_amdgcn_sched_barrier(0);
        __builtin_amdgcn_s_setprio(1);
        MM(a, b, acc[0][1]);
        __builtin_amdgcn_s_setprio(0);
        __builtin_amdgcn_s_barrier();
        __builtin_amdgcn_sched_barrier(0);
        // ---------- phase 2: (1, 1) ----------
        LDA(pb, 1, a);                                 // 8 ds_read_b128
        if (t + 2 < NT) STAGE(pb, 0, 0, t + 2);        // A0(t+2)
        __builtin_amdgcn_s_barrier();
        asm volatile("s_waitcnt lgkmcnt(0)" ::: "memory");
        __builtin_amdgcn_sched_barrier(0);
        __builtin_amdgcn_s_setprio(1);
        MM(a, b, acc[1][1]);
        __builtin_amdgcn_s_setprio(0);
        __builtin_amdgcn_s_barrier();
        __builtin_amdgcn_sched_barrier(0);
        // ---------- phase 3: (1, 0) ----------
        LDB(pb, 0, b);                                 // 4 ds_read_b128 (reload B0)
        if (t + 2 < NT) STAGE(pb, 1, 1, t + 2);        // B1(t+2)
        if (t + 1 < NT) {
            asm volatile("s_waitcnt vmcnt(4)" ::: "memory");  // tile t+1 ready
        } else {
            asm volatile("s_waitcnt vmcnt(0)" ::: "memory");
        }
        __builtin_amdgcn_s_barrier();
        asm volatile("s_waitcnt lgkmcnt(0)" ::: "memory");
        __builtin_amdgcn_sched_barrier(0);
        __builtin_amdgcn_s_setprio(1);
        MM(a, b, acc[1][0]);
        __builtin_amdgcn_s_setprio(0);
        __builtin_amdgcn_s_barrier();
        __builtin_amdgcn_sched_barrier(0);
    }

    // ---- epilogue ----
#pragma unroll
    for (int qi = 0; qi < 2; ++qi)
#pragma unroll
    for (int i = 0; i < 4; ++i)
#pragma unroll
    for (int qj = 0; qj < 2; ++qj)
#pragma unroll
    for (int j = 0; j < 2; ++j) {
        long col = bn + c * 32 + qj * 128 + j * 16 + cn;
        float bv = bias[col];
#pragma unroll
        for (int r = 0; r < 4; ++r) {
            long row = bm + g * 64 + qi * 128 + i * 16 + rq + r;
            float v = acc[qi][qj][i][j][r] + bv;
            if (MODE == 0) {
                Cb[row * N + col] = f2b(v);
            } else if (MODE == 1) {
                Cf[row * N + col] = v + resid[row * N + col];
            } else {
                float ge = 0.5f * v * (1.0f + erff(v * 0.70710678118654752f));
                Cb[row * N + col] = f2b(ge);
            }
        }
    }
}

// ---------------------------------------------------------------------------
// MFMA flash attention (round-0 measured-best version, 149 us).
// 64 q-rows per block, 4 waves x 16 rows; fixed-shift softmax exp(s+mask-8).
// All LDS tiles stride 64 with XOR chunk swizzle -> conflict-free b128 reads.
// V pre-transposed in global (vtg). Q frags hoisted out of the k-loop.
// ---------------------------------------------------------------------------
__global__ __launch_bounds__(256, 2)
void attn_kernel(const __bf16* __restrict__ QKV, const __bf16* __restrict__ VT,
                 const float* __restrict__ mask, __bf16* __restrict__ ctx)
{
    __shared__ __bf16 Qs[64 * 64];     // [qrow][d]   swizzled chunks
    __shared__ __bf16 Ks[64 * 64];     // [key][d]    swizzled chunks
    __shared__ __bf16 Vt[64 * 64];     // [d][key]    swizzled chunks
    __shared__ __bf16 Ps[64 * 64];     // [qrow][key] swizzled chunks

    const int tid  = threadIdx.x;
    const int lane = tid & 63;
    const int wave = tid >> 6;
    const int w16  = wave * 16;
    const int b    = blockIdx.z, h = blockIdx.y;
    const int q0   = blockIdx.x * 64;
    const int cn   = lane & 15;
    const int quad = lane >> 4;
    const int rq   = quad * 4;
    const int koff0 = ((0 * 4 + quad) ^ (cn & 7)) * 8;
    const int koff1 = ((1 * 4 + quad) ^ (cn & 7)) * 8;

    // stage Q (async, swizzled)
#pragma unroll
    for (int t = 0; t < 2; ++t) {
        int ci = tid + t * 256;
        int qr = ci >> 3, dc = ((ci & 7) ^ (qr & 7)) << 3;
        async_ld16(QKV + (long)(b * S_ + q0 + qr) * 3072 + h * 64 + dc,
                   &Qs[ci * 8]);
    }
    __syncthreads();   // Q landed
    const bf16x8 aq0 = *(const bf16x8*)&Qs[(w16 + cn) * 64 + koff0];
    const bf16x8 aq1 = *(const bf16x8*)&Qs[(w16 + cn) * 64 + koff1];

    float l_[4];
    floatx4 o_[4];
#pragma unroll
    for (int r = 0; r < 4; ++r) l_[r] = 0.0f;
#pragma unroll
    for (int jt = 0; jt < 4; ++jt)
#pragma unroll
        for (int r = 0; r < 4; ++r) o_[jt][r] = 0.0f;

    const long vbase = ((long)(b * H_ + h) * 64) * S_;   // vtg row base

    for (int k0 = 0; k0 < S_; k0 += 64) {
        __syncthreads();   // previous tile's reads complete
#pragma unroll
        for (int t = 0; t < 2; ++t) {
            int ci = tid + t * 256;
            int kr = ci >> 3, dc = ((ci & 7) ^ (kr & 7)) << 3;
            async_ld16(QKV + (long)(b * S_ + k0 + kr) * 3072 + 1024 + h * 64 + dc,
                       &Ks[ci * 8]);
            int vd = ci >> 3, kc = ((ci & 7) ^ (vd & 7)) << 3;
            async_ld16(VT + vbase + (long)vd * S_ + k0 + kc, &Vt[ci * 8]);
        }
        __syncthreads();   // staging landed

        // ---- S = Q K^T ----
        floatx4 st[4];
#pragma unroll
        for (int jt = 0; jt < 4; ++jt)
#pragma unroll
            for (int r = 0; r < 4; ++r) st[jt][r] = 0.0f;
#pragma unroll
        for (int jt = 0; jt < 4; ++jt) {
            bf16x8 b0 = *(const bf16x8*)&Ks[(jt * 16 + cn) * 64 + koff0];
            bf16x8 b1 = *(const bf16x8*)&Ks[(jt * 16 + cn) * 64 + koff1];
            st[jt] = __builtin_amdgcn_mfma_f32_16x16x32_bf16(aq0, b0, st[jt], 0, 0, 0);
            st[jt] = __builtin_amdgcn_mfma_f32_16x16x32_bf16(aq1, b1, st[jt], 0, 0, 0);
        }
        // ---- p = exp(s + mask - 8); per-lane partial row sums ----
#pragma unroll
        for (int jt = 0; jt < 4; ++jt) {
            float mv = mask[(long)b * S_ + k0 + jt * 16 + cn] - 8.0f;
#pragma unroll
            for (int r = 0; r < 4; ++r) {
                float p = __expf(st[jt][r] + mv);
                st[jt][r] = p;
                l_[r] += p;
            }
        }
        // ---- P -> LDS (swizzled chunks; DS pipe in-order per wave) ----
#pragma unroll
        for (int jt = 0; jt < 4; ++jt)
#pragma unroll
            for (int r = 0; r < 4; ++r) {
                int prow = w16 + rq + r;
                int pcol = (((jt * 2 + (cn >> 3)) ^ (prow & 7)) << 3) + (cn & 7);
                Ps[prow * 64 + pcol] = f2b(st[jt][r]);
            }

        // ---- O += P V ----
        {
            bf16x8 ap0 = *(const bf16x8*)&Ps[(w16 + cn) * 64 + koff0];
            bf16x8 ap1 = *(const bf16x8*)&Ps[(w16 + cn) * 64 + koff1];
#pragma unroll
            for (int jt = 0; jt < 4; ++jt) {
                bf16x8 b0 = *(const bf16x8*)&Vt[(jt * 16 + cn) * 64 + koff0];
                bf16x8 b1 = *(const bf16x8*)&Vt[(jt * 16 + cn) * 64 + koff1];
                o_[jt] = __builtin_amdgcn_mfma_f32_16x16x32_bf16(ap0, b0, o_[jt], 0, 0, 0);
                o_[jt] = __builtin_amdgcn_mfma_f32_16x16x32_bf16(ap1, b1, o_[jt], 0, 0, 0);
            }
        }
    }

    // final row-sum reduce + normalize + store
#pragma unroll
    for (int r = 0; r < 4; ++r) {
        float l = l_[r];
        l += __shfl_xor(l, 1);
        l += __shfl_xor(l, 2);
        l += __shfl_xor(l, 4);
        l += __shfl_xor(l, 8);
        float linv = 1.0f / l;
        long rowg = (long)(b * S_ + q0 + w16 + rq + r) * D_ + h * 64;
#pragma unroll
        for (int jt = 0; jt < 4; ++jt)
            ctx[rowg + jt * 16 + cn] = f2b(o_[jt][r] * linv);
    }
}

// ---------------------------------------------------------------------------
// Row LayerNorm, row length 1024. Writes fp32 out and (optionally) bf16 copy.
// ---------------------------------------------------------------------------
__global__ __launch_bounds__(256)
void ln_kernel(const float* __restrict__ X, const float* __restrict__ gamma,
               const float* __restrict__ beta, float* __restrict__ out,
               __bf16* __restrict__ outb)
{
    const long row = blockIdx.x;
    const int tid = threadIdx.x;
    const float* x = X + row * D_;
    float4 v = *(const float4*)&x[tid * 4];
    float s  = v.x + v.y + v.z + v.w;
    float s2 = v.x * v.x + v.y * v.y + v.z * v.z + v.w * v.w;
    for (int off = 32; off > 0; off >>= 1) {
        s  += __shfl_down(s, off);
        s2 += __shfl_down(s2, off);
    }
    __shared__ float red[8];
    int wave = tid >> 6, lane = tid & 63;
    if (lane == 0) { red[wave] = s; red[4 + wave] = s2; }
    __syncthreads();
    float ts  = red[0] + red[1] + red[2] + red[3];
    float ts2 = red[4] + red[5] + red[6] + red[7];
    float mu  = ts * (1.0f / D_);
    float var = ts2 * (1.0f / D_) - mu * mu;
    float rs  = rsqrtf(fmaxf(var, 0.0f) + 1e-12f);
    float4 g = *(const float4*)&gamma[tid * 4];
    float4 b = *(const float4*)&beta[tid * 4];
    float4 o;
    o.x = (v.x - mu) * rs * g.x + b.x;
    o.y = (v.y - mu) * rs * g.y + b.y;
    o.z = (v.z - mu) * rs * g.z + b.z;
    o.w = (v.w - mu) * rs * g.w + b.w;
    *(float4*)&out[row * D_ + tid * 4] = o;
    if (outb) {
        bf16x4 ob;
        ob[0] = f2b(o.x); ob[1] = f2b(o.y); ob[2] = f2b(o.z); ob[3] = f2b(o.w);
        *(bf16x4*)&outb[row * D_ + tid * 4] = ob;
    }
}

// ---------------------------------------------------------------------------
extern "C" void kernel_launch(void* const* d_in, const int* in_sizes, int n_in,
                              void* d_out, int out_size, void* d_ws, size_t ws_size,
                              hipStream_t stream)
{
    const float* hid  = (const float*)d_in[0];
    const float* mask = (const float*)d_in[1];
    const float* Wq   = (const float*)d_in[2];
    const float* bq   = (const float*)d_in[3];
    const float* Wk   = (const float*)d_in[4];
    const float* bk   = (const float*)d_in[5];
    const float* Wv   = (const float*)d_in[6];
    const float* bv   = (const float*)d_in[7];
    const float* Wo   = (const float*)d_in[8];
    const float* bo   = (const float*)d_in[9];
    const float* g1   = (const float*)d_in[10];
    const float* b1   = (const float*)d_in[11];
    const float* Wi   = (const float*)d_in[12];
    const float* bi   = (const float*)d_in[13];
    const float* Wo2  = (const float*)d_in[14];
    const float* bo2  = (const float*)d_in[15];
    const float* g2   = (const float*)d_in[16];
    const float* b2   = (const float*)d_in[17];
    float* out = (float*)d_out;

    char* w = (char*)d_ws;
    auto take = [&](size_t bytes) { char* p = w; w += bytes; return p; };
    __bf16* wqkvb = (__bf16*)take((size_t)3 * D_ * D_ * 2);  // [3072][1024]
    __bf16* wob   = (__bf16*)take((size_t)D_ * D_ * 2);
    __bf16* wib   = (__bf16*)take((size_t)D_ * DFF_ * 2);
    __bf16* wo2b  = (__bf16*)take((size_t)D_ * DFF_ * 2);
    float*  qkvbias = (float*)take(16384);
    __bf16* qkv   = (__bf16*)take((size_t)M_ * 3 * D_ * 2);  // 48MB
    __bf16* ctxb  = (__bf16*)take((size_t)M_ * D_ * 2);      // 16MB
    __bf16* hb    = (__bf16*)take((size_t)M_ * D_ * 2);      // 16MB
    float*  tmp      = (float*)take((size_t)M_ * D_ * 4);
    float*  attn_out = (float*)take((size_t)M_ * D_ * 4);
    // aliases (regions dead by the time these are used):
    __bf16* hbuf = qkv;       // FFN hidden [M][4096] = 64MB over qkv+ctxb
    __bf16* vtg  = hb;        // hb dead after QKV GEMM; vtg dead after attn
    __bf16* attn_out_b = hb;  // written at ln1 (after attn)
    (void)in_sizes; (void)n_in; (void)out_size; (void)ws_size;

    dim3 tb(32, 8);
    transpose_conv_kernel<<<dim3(D_/32, D_/32), tb, 0, stream>>>(Wq, wqkvb,            D_, D_, 0.125f);
    transpose_conv_kernel<<<dim3(D_/32, D_/32), tb, 0, stream>>>(Wk, wqkvb + D_*D_,    D_, D_, 1.0f);
    transpose_conv_kernel<<<dim3(D_/32, D_/32), tb, 0, stream>>>(Wv, wqkvb + 2*D_*D_,  D_, D_, 1.0f);
    transpose_conv_kernel<<<dim3(D_/32, D_/32), tb, 0, stream>>>(Wo, wob, D_, D_, 1.0f);
    transpose_conv_kernel<<<dim3(DFF_/32, D_/32), tb, 0, stream>>>(Wi, wib, D_, DFF_, 1.0f);
    transpose_conv_kernel<<<dim3(D_/32, DFF_/32), tb, 0, stream>>>(Wo2, wo2b, DFF_, D_, 1.0f);
    bias_concat_kernel<<<12, 256, 0, stream>>>(bq, bk, bv, qkvbias);
    f2b_kernel<<<(M_*D_/8 + 255)/256, 256, 0, stream>>>(hid, hb, (long)M_*D_);

    // fused QKV projection: [8192,1024] x [1024,3072]  (256^2 8-phase)
    gemm256_kernel<0><<<dim3(3*D_/256, M_/256), 512, 0, stream>>>(
        hb, wqkvb, qkvbias, nullptr, nullptr, qkv, M_, 3*D_, D_);

    // V -> vtg[b][h][d][s]
    vt_transpose_kernel<<<dim3(S_/32, H_*2, B_), tb, 0, stream>>>(qkv, vtg);

    attn_kernel<<<dim3(S_/64, H_, B_), 256, 0, stream>>>(qkv, vtg, mask, ctxb);

    // attn out projection + residual (fp32 hid) -> tmp   (N=1024: 128^2 kernel)
    gemm_kernel<1><<<dim3(D_/128, M_/128), 256, 0, stream>>>(
        ctxb, wob, bo, hid, tmp, nullptr, M_, D_, D_);
    ln_kernel<<<M_, 256, 0, stream>>>(tmp, g1, b1, attn_out, attn_out_b);

    // FFN1: [8192,1024] x [1024,4096] gelu  (256^2 8-phase)
    gemm256_kernel<2><<<dim3(DFF_/256, M_/256), 512, 0, stream>>>(
        attn_out_b, wib, bi, nullptr, nullptr, hbuf, M_, DFF_, D_);
    // FFN2: N=1024 -> 128^2 kernel
    gemm_kernel<1><<<dim3(D_/128, M_/128), 256, 0, stream>>>(
        hbuf, wo2b, bo2, attn_out, tmp, nullptr, M_, D_, DFF_);
    ln_kernel<<<M_, 256, 0, stream>>>(tmp, g2, b2, out, nullptr);
}

// Round 3
// 569.043 us; speedup vs baseline: 1.0945x; 1.0945x over previous
//
#include <hip/hip_runtime.h>
#include <hip/hip_bf16.h>
#include <math.h>

#define B_   4
#define S_   2048
#define D_   1024
#define H_   16
#define HD_  64
#define DFF_ 4096
#define M_   (B_*S_)   // 8192 rows

typedef __bf16 bf16x8 __attribute__((ext_vector_type(8)));
typedef __bf16 bf16x4 __attribute__((ext_vector_type(4)));
typedef float  floatx4 __attribute__((ext_vector_type(4)));

__device__ __forceinline__ float  b2f(__bf16 v) { return (float)v; }
__device__ __forceinline__ __bf16 f2b(float v)  { return (__bf16)v; }

// async global->LDS, 16 bytes per lane. LDS dests MUST be base + lane*16.
__device__ __forceinline__ void async_ld16(const void* g, void* l) {
    __builtin_amdgcn_global_load_lds(
        (const __attribute__((address_space(1))) unsigned int*)g,
        (__attribute__((address_space(3))) unsigned int*)l, 16, 0, 0);
}

// ---------------------------------------------------------------------------
// Transpose + convert + scale: out[c*R + r] = bf16(in[r*C + c] * scale).
// ---------------------------------------------------------------------------
__global__ void transpose_conv_kernel(const float* __restrict__ in,
                                      __bf16* __restrict__ out, int R, int C,
                                      float scale)
{
    __shared__ float t[32][33];
    int c0 = blockIdx.x * 32, r0 = blockIdx.y * 32;
    int tx = threadIdx.x, ty = threadIdx.y;
    for (int i = ty; i < 32; i += 8)
        t[i][tx] = in[(long)(r0 + i) * C + c0 + tx];
    __syncthreads();
    for (int i = ty; i < 32; i += 8)
        out[(long)(c0 + i) * R + r0 + tx] = f2b(t[tx][i] * scale);
}

// bf16 V -> global transposed vtg[b][h][d][s]  (once; frees attn inner loop)
__global__ void vt_transpose_kernel(const __bf16* __restrict__ qkv,
                                    __bf16* __restrict__ vtg)
{
    __shared__ __bf16 t[32][34];
    int b  = blockIdx.z;
    int h  = blockIdx.y >> 1;
    int d0 = (blockIdx.y & 1) * 32;
    int s0 = blockIdx.x * 32;
    int tx = threadIdx.x, ty = threadIdx.y;
    for (int i = ty; i < 32; i += 8)
        t[i][tx] = qkv[(long)(b * S_ + s0 + i) * 3072 + 2048 + h * 64 + d0 + tx];
    __syncthreads();
    for (int i = ty; i < 32; i += 8)
        vtg[((long)(b * H_ + h) * 64 + d0 + i) * S_ + s0 + tx] = t[tx][i];
}

// fp32 -> bf16 elementwise (n multiple of 8)
__global__ void f2b_kernel(const float* __restrict__ in, __bf16* __restrict__ out,
                           long n)
{
    long i = ((long)blockIdx.x * 256 + threadIdx.x) * 8;
    if (i >= n) return;
    float4 a = *(const float4*)&in[i];
    float4 c = *(const float4*)&in[i + 4];
    union { __bf16 h[8]; uint4 u; } p;
    p.h[0] = f2b(a.x); p.h[1] = f2b(a.y); p.h[2] = f2b(a.z); p.h[3] = f2b(a.w);
    p.h[4] = f2b(c.x); p.h[5] = f2b(c.y); p.h[6] = f2b(c.z); p.h[7] = f2b(c.w);
    *(uint4*)&out[i] = p.u;
}

// concat q/k/v biases; q part scaled by 0.125 (score scale folded into Wq,bq)
__global__ void bias_concat_kernel(const float* __restrict__ bq,
                                   const float* __restrict__ bk,
                                   const float* __restrict__ bv,
                                   float* __restrict__ dst)
{
    int i = blockIdx.x * 256 + threadIdx.x;
    if (i >= 3 * D_) return;
    float v = (i < D_) ? bq[i] * 0.125f
            : (i < 2 * D_) ? bk[i - D_] : bv[i - 2 * D_];
    dst[i] = v;
}

// ---------------------------------------------------------------------------
// bf16 MFMA GEMM (m97 structure + XOR bank-swizzle): C = A[M,K] * Bt[N,K]^T
//   MODE 0: Cb = bf16(acc + bias)
//   MODE 1: Cf = acc + bias + resid       (fp32, feeds LayerNorm)
//   MODE 2: Cb = bf16(gelu(acc + bias))
// ---------------------------------------------------------------------------
template<int MODE>
__global__ __launch_bounds__(256, 2)
void gemm_kernel(const __bf16* __restrict__ A, const __bf16* __restrict__ Bt,
                 const float* __restrict__ bias, const float* __restrict__ resid,
                 float* __restrict__ Cf, __bf16* __restrict__ Cb,
                 int M, int N, int K)
{
    __shared__ __bf16 sA[128 * 64];
    __shared__ __bf16 sB[128 * 64];

    const int tid  = threadIdx.x;
    const int lane = tid & 63;
    const int wave = tid >> 6;
    const int wm   = (wave >> 1) * 64;
    const int wn   = (wave & 1) * 64;
    const long bm  = (long)blockIdx.y * 128;
    const long bn  = (long)blockIdx.x * 128;

    floatx4 acc[4][4];
#pragma unroll
    for (int i = 0; i < 4; ++i)
#pragma unroll
        for (int j = 0; j < 4; ++j)
#pragma unroll
            for (int r = 0; r < 4; ++r) acc[i][j][r] = 0.0f;

    const int mrow = lane & 15;
    const int quad = lane >> 4;
    const int koff0 = ((0 * 4 + quad) ^ (mrow & 7)) * 8;
    const int koff1 = ((1 * 4 + quad) ^ (mrow & 7)) * 8;

    for (int k0 = 0; k0 < K; k0 += 64) {
        __syncthreads();
#pragma unroll
        for (int t = 0; t < 4; ++t) {
            int ci  = tid + t * 256;
            int row = ci >> 3;
            int col = ((ci & 7) ^ (row & 7)) << 3;   // XOR swizzle on global
            async_ld16(A  + (bm + row) * (long)K + k0 + col, &sA[ci * 8]);
            async_ld16(Bt + (bn + row) * (long)K + k0 + col, &sB[ci * 8]);
        }
        __syncthreads();

#pragma unroll
        for (int s = 0; s < 2; ++s) {
            const int ko = s ? koff1 : koff0;
            bf16x8 a[4], b[4];
#pragma unroll
            for (int i = 0; i < 4; ++i)
                a[i] = *(const bf16x8*)&sA[(wm + i * 16 + mrow) * 64 + ko];
#pragma unroll
            for (int j = 0; j < 4; ++j)
                b[j] = *(const bf16x8*)&sB[(wn + j * 16 + mrow) * 64 + ko];
#pragma unroll
            for (int i = 0; i < 4; ++i)
#pragma unroll
                for (int j = 0; j < 4; ++j)
                    acc[i][j] = __builtin_amdgcn_mfma_f32_16x16x32_bf16(
                        a[i], b[j], acc[i][j], 0, 0, 0);
        }
    }

    // D: row = quad*4 + reg, col = lane&15   [verified m89/m91]
    const int rq = quad * 4;
    const int cn = lane & 15;
#pragma unroll
    for (int i = 0; i < 4; ++i) {
#pragma unroll
        for (int j = 0; j < 4; ++j) {
            long col = bn + wn + j * 16 + cn;
            float bv = bias[col];
#pragma unroll
            for (int r = 0; r < 4; ++r) {
                long row = bm + wm + i * 16 + rq + r;
                float v = acc[i][j][r] + bv;
                if (MODE == 0) {
                    Cb[row * N + col] = f2b(v);
                } else if (MODE == 1) {
                    Cf[row * N + col] = v + resid[row * N + col];
                } else {
                    float g = 0.5f * v * (1.0f + erff(v * 0.70710678118654752f));
                    Cb[row * N + col] = f2b(g);
                }
            }
        }
    }
}

// ---------------------------------------------------------------------------
// MFMA flash attention v3: round-0 structure (QBLK=64, 4 waves x 16 q-rows,
// grid 2048 blocks) + double-buffered K/V staging:
//   * Ks[2]/Vt[2] (32KB) + Ps (8KB, aliases the Q staging buffer) = 40KB
//     -> exactly 4 blocks/CU, grid 2048 = exactly 2 residency rounds
//   * per iter: issue next tile's global_load_lds FIRST, then compute current
//     tile, then ONE vmcnt(0)+barrier (loads had the whole compute phase to
//     land -> staging latency hidden; round-0 had a fully-exposed drain)
//   * hazard ledger: buf[cur^1] overwrite issued >=1 barrier after its last
//     read; buf[cur] reads covered by prev iter's vmcnt(0)+barrier; Ps rows
//     are wave-private (DS in-order per wave) so Q-alias and P round-trip
//     need no barrier.
//   * fixed-shift softmax exp(s+mask-8) (shift-invariant for zero-mask rows)
//   * all LDS tiles stride 64 with XOR chunk swizzle -> conflict-free b128
// ---------------------------------------------------------------------------
__global__ __launch_bounds__(256, 2)
void attn_kernel(const __bf16* __restrict__ QKV, const __bf16* __restrict__ VT,
                 const float* __restrict__ mask, __bf16* __restrict__ ctx)
{
    __shared__ __bf16 Ks[2][64 * 64];  // [buf][key][d]  swizzled chunks
    __shared__ __bf16 Vt[2][64 * 64];  // [buf][d][key]  swizzled chunks
    __shared__ __bf16 Ps[64 * 64];     // [qrow][key]; also Q staging buffer

    const int tid  = threadIdx.x;
    const int lane = tid & 63;
    const int wave = tid >> 6;
    const int w16  = wave * 16;
    const int b    = blockIdx.z, h = blockIdx.y;
    const int q0   = blockIdx.x * 64;
    const int cn   = lane & 15;
    const int quad = lane >> 4;
    const int rq   = quad * 4;
    const int koff0 = ((0 * 4 + quad) ^ (cn & 7)) * 8;
    const int koff1 = ((1 * 4 + quad) ^ (cn & 7)) * 8;

    const long vbase = ((long)(b * H_ + h) * 64) * S_;   // vtg row base

    auto STAGE = [&](int bufi, int k0) {
#pragma unroll
        for (int t = 0; t < 2; ++t) {
            int ci = tid + t * 256;
            int r  = ci >> 3;
            int cz = ((ci & 7) ^ (r & 7)) << 3;
            async_ld16(QKV + (long)(b * S_ + k0 + r) * 3072 + 1024 + h * 64 + cz,
                       &Ks[bufi][ci * 8]);
            async_ld16(VT + vbase + (long)r * S_ + k0 + cz, &Vt[bufi][ci * 8]);
        }
    };

    // ---- prologue: stage Q (into Ps) + tile 0 ----
#pragma unroll
    for (int t = 0; t < 2; ++t) {
        int ci = tid + t * 256;
        int qr = ci >> 3, dc = ((ci & 7) ^ (qr & 7)) << 3;
        async_ld16(QKV + (long)(b * S_ + q0 + qr) * 3072 + h * 64 + dc,
                   &Ps[ci * 8]);
    }
    STAGE(0, 0);
    asm volatile("s_waitcnt vmcnt(0)" ::: "memory");
    __builtin_amdgcn_s_barrier();
    __builtin_amdgcn_sched_barrier(0);

    // Q fragments (wave-private rows of Ps; Ps reused for P after this)
    const bf16x8 aq0 = *(const bf16x8*)&Ps[(w16 + cn) * 64 + koff0];
    const bf16x8 aq1 = *(const bf16x8*)&Ps[(w16 + cn) * 64 + koff1];

    float l_[4];
    floatx4 o_[4];
#pragma unroll
    for (int r = 0; r < 4; ++r) l_[r] = 0.0f;
#pragma unroll
    for (int jt = 0; jt < 4; ++jt)
#pragma unroll
        for (int r = 0; r < 4; ++r) o_[jt][r] = 0.0f;

    int cur = 0;
    for (int k0 = 0; k0 < S_; k0 += 64) {
        // issue next tile's loads (buf[cur^1] last read ended >=1 barrier ago)
        if (k0 + 64 < S_) STAGE(cur ^ 1, k0 + 64);

        // ---- S = Q K^T ----  (buf[cur] landed: prev iter's vmcnt(0)+barrier)
        floatx4 st[4];
#pragma unroll
        for (int jt = 0; jt < 4; ++jt)
#pragma unroll
            for (int r = 0; r < 4; ++r) st[jt][r] = 0.0f;
#pragma unroll
        for (int jt = 0; jt < 4; ++jt) {
            bf16x8 b0 = *(const bf16x8*)&Ks[cur][(jt * 16 + cn) * 64 + koff0];
            bf16x8 b1 = *(const bf16x8*)&Ks[cur][(jt * 16 + cn) * 64 + koff1];
            st[jt] = __builtin_amdgcn_mfma_f32_16x16x32_bf16(aq0, b0, st[jt], 0, 0, 0);
            st[jt] = __builtin_amdgcn_mfma_f32_16x16x32_bf16(aq1, b1, st[jt], 0, 0, 0);
        }
        // ---- p = exp(s + mask - 8); per-lane partial row sums ----
#pragma unroll
        for (int jt = 0; jt < 4; ++jt) {
            float mv = mask[(long)b * S_ + k0 + jt * 16 + cn] - 8.0f;
#pragma unroll
            for (int r = 0; r < 4; ++r) {
                float p = __expf(st[jt][r] + mv);
                st[jt][r] = p;
                l_[r] += p;
            }
        }
        // ---- P -> LDS (wave-private rows; DS pipe in-order per wave) ----
#pragma unroll
        for (int jt = 0; jt < 4; ++jt)
#pragma unroll
            for (int r = 0; r < 4; ++r) {
                int prow = w16 + rq + r;
                int pcol = (((jt * 2 + (cn >> 3)) ^ (prow & 7)) << 3) + (cn & 7);
                Ps[prow * 64 + pcol] = f2b(st[jt][r]);
            }

        // ---- O += P V ----
        {
            bf16x8 ap0 = *(const bf16x8*)&Ps[(w16 + cn) * 64 + koff0];
            bf16x8 ap1 = *(const bf16x8*)&Ps[(w16 + cn) * 64 + koff1];
#pragma unroll
            for (int jt = 0; jt < 4; ++jt) {
                bf16x8 b0 = *(const bf16x8*)&Vt[cur][(jt * 16 + cn) * 64 + koff0];
                bf16x8 b1 = *(const bf16x8*)&Vt[cur][(jt * 16 + cn) * 64 + koff1];
                o_[jt] = __builtin_amdgcn_mfma_f32_16x16x32_bf16(ap0, b0, o_[jt], 0, 0, 0);
                o_[jt] = __builtin_amdgcn_mfma_f32_16x16x32_bf16(ap1, b1, o_[jt], 0, 0, 0);
            }
        }

        // next tile's loads had the whole compute phase to land; drain + sync
        asm volatile("s_waitcnt vmcnt(0) lgkmcnt(0)" ::: "memory");
        __builtin_amdgcn_s_barrier();
        __builtin_amdgcn_sched_barrier(0);
        cur ^= 1;
    }

    // final row-sum reduce + normalize + store
#pragma unroll
    for (int r = 0; r < 4; ++r) {
        float l = l_[r];
        l += __shfl_xor(l, 1);
        l += __shfl_xor(l, 2);
        l += __shfl_xor(l, 4);
        l += __shfl_xor(l, 8);
        float linv = 1.0f / l;
        long rowg = (long)(b * S_ + q0 + w16 + rq + r) * D_ + h * 64;
#pragma unroll
        for (int jt = 0; jt < 4; ++jt)
            ctx[rowg + jt * 16 + cn] = f2b(o_[jt][r] * linv);
    }
}

// ---------------------------------------------------------------------------
// Row LayerNorm, row length 1024. Writes fp32 out and (optionally) bf16 copy.
// ---------------------------------------------------------------------------
__global__ __launch_bounds__(256)
void ln_kernel(const float* __restrict__ X, const float* __restrict__ gamma,
               const float* __restrict__ beta, float* __restrict__ out,
               __bf16* __restrict__ outb)
{
    const long row = blockIdx.x;
    const int tid = threadIdx.x;
    const float* x = X + row * D_;
    float4 v = *(const float4*)&x[tid * 4];
    float s  = v.x + v.y + v.z + v.w;
    float s2 = v.x * v.x + v.y * v.y + v.z * v.z + v.w * v.w;
    for (int off = 32; off > 0; off >>= 1) {
        s  += __shfl_down(s, off);
        s2 += __shfl_down(s2, off);
    }
    __shared__ float red[8];
    int wave = tid >> 6, lane = tid & 63;
    if (lane == 0) { red[wave] = s; red[4 + wave] = s2; }
    __syncthreads();
    float ts  = red[0] + red[1] + red[2] + red[3];
    float ts2 = red[4] + red[5] + red[6] + red[7];
    float mu  = ts * (1.0f / D_);
    float var = ts2 * (1.0f / D_) - mu * mu;
    float rs  = rsqrtf(fmaxf(var, 0.0f) + 1e-12f);
    float4 g = *(const float4*)&gamma[tid * 4];
    float4 b = *(const float4*)&beta[tid * 4];
    float4 o;
    o.x = (v.x - mu) * rs * g.x + b.x;
    o.y = (v.y - mu) * rs * g.y + b.y;
    o.z = (v.z - mu) * rs * g.z + b.z;
    o.w = (v.w - mu) * rs * g.w + b.w;
    *(float4*)&out[row * D_ + tid * 4] = o;
    if (outb) {
        bf16x4 ob;
        ob[0] = f2b(o.x); ob[1] = f2b(o.y); ob[2] = f2b(o.z); ob[3] = f2b(o.w);
        *(bf16x4*)&outb[row * D_ + tid * 4] = ob;
    }
}

// ---------------------------------------------------------------------------
extern "C" void kernel_launch(void* const* d_in, const int* in_sizes, int n_in,
                              void* d_out, int out_size, void* d_ws, size_t ws_size,
                              hipStream_t stream)
{
    const float* hid  = (const float*)d_in[0];
    const float* mask = (const float*)d_in[1];
    const float* Wq   = (const float*)d_in[2];
    const float* bq   = (const float*)d_in[3];
    const float* Wk   = (const float*)d_in[4];
    const float* bk   = (const float*)d_in[5];
    const float* Wv   = (const float*)d_in[6];
    const float* bv   = (const float*)d_in[7];
    const float* Wo   = (const float*)d_in[8];
    const float* bo   = (const float*)d_in[9];
    const float* g1   = (const float*)d_in[10];
    const float* b1   = (const float*)d_in[11];
    const float* Wi   = (const float*)d_in[12];
    const float* bi   = (const float*)d_in[13];
    const float* Wo2  = (const float*)d_in[14];
    const float* bo2  = (const float*)d_in[15];
    const float* g2   = (const float*)d_in[16];
    const float* b2   = (const float*)d_in[17];
    float* out = (float*)d_out;

    char* w = (char*)d_ws;
    auto take = [&](size_t bytes) { char* p = w; w += bytes; return p; };
    __bf16* wqkvb = (__bf16*)take((size_t)3 * D_ * D_ * 2);  // [3072][1024]
    __bf16* wob   = (__bf16*)take((size_t)D_ * D_ * 2);
    __bf16* wib   = (__bf16*)take((size_t)D_ * DFF_ * 2);
    __bf16* wo2b  = (__bf16*)take((size_t)D_ * DFF_ * 2);
    float*  qkvbias = (float*)take(16384);
    __bf16* qkv   = (__bf16*)take((size_t)M_ * 3 * D_ * 2);  // 48MB
    __bf16* ctxb  = (__bf16*)take((size_t)M_ * D_ * 2);      // 16MB
    __bf16* hb    = (__bf16*)take((size_t)M_ * D_ * 2);      // 16MB
    float*  tmp      = (float*)take((size_t)M_ * D_ * 4);
    float*  attn_out = (float*)take((size_t)M_ * D_ * 4);
    // aliases (regions dead by the time these are used):
    __bf16* hbuf = qkv;       // FFN hidden [M][4096] = 64MB over qkv+ctxb
    __bf16* vtg  = hb;        // hb dead after QKV GEMM; vtg dead after attn
    __bf16* attn_out_b = hb;  // written at ln1 (after attn)
    (void)in_sizes; (void)n_in; (void)out_size; (void)ws_size;

    dim3 tb(32, 8);
    transpose_conv_kernel<<<dim3(D_/32, D_/32), tb, 0, stream>>>(Wq, wqkvb,            D_, D_, 0.125f);
    transpose_conv_kernel<<<dim3(D_/32, D_/32), tb, 0, stream>>>(Wk, wqkvb + D_*D_,    D_, D_, 1.0f);
    transpose_conv_kernel<<<dim3(D_/32, D_/32), tb, 0, stream>>>(Wv, wqkvb + 2*D_*D_,  D_, D_, 1.0f);
    transpose_conv_kernel<<<dim3(D_/32, D_/32), tb, 0, stream>>>(Wo, wob, D_, D_, 1.0f);
    transpose_conv_kernel<<<dim3(DFF_/32, D_/32), tb, 0, stream>>>(Wi, wib, D_, DFF_, 1.0f);
    transpose_conv_kernel<<<dim3(D_/32, DFF_/32), tb, 0, stream>>>(Wo2, wo2b, DFF_, D_, 1.0f);
    bias_concat_kernel<<<12, 256, 0, stream>>>(bq, bk, bv, qkvbias);
    f2b_kernel<<<(M_*D_/8 + 255)/256, 256, 0, stream>>>(hid, hb, (long)M_*D_);

    // fused QKV projection: [8192,1024] x [1024,3072]
    gemm_kernel<0><<<dim3(3*D_/128, M_/128), 256, 0, stream>>>(
        hb, wqkvb, qkvbias, nullptr, nullptr, qkv, M_, 3*D_, D_);

    // V -> vtg[b][h][d][s]
    vt_transpose_kernel<<<dim3(S_/32, H_*2, B_), tb, 0, stream>>>(qkv, vtg);

    attn_kernel<<<dim3(S_/64, H_, B_), 256, 0, stream>>>(qkv, vtg, mask, ctxb);

    // attn out projection + residual (fp32 hid) -> tmp
    gemm_kernel<1><<<dim3(D_/128, M_/128), 256, 0, stream>>>(
        ctxb, wob, bo, hid, tmp, nullptr, M_, D_, D_);
    ln_kernel<<<M_, 256, 0, stream>>>(tmp, g1, b1, attn_out, attn_out_b);

    // FFN
    gemm_kernel<2><<<dim3(DFF_/128, M_/128), 256, 0, stream>>>(
        attn_out_b, wib, bi, nullptr, nullptr, hbuf, M_, DFF_, D_);
    gemm_kernel<1><<<dim3(D_/128, M_/128), 256, 0, stream>>>(
        hbuf, wo2b, bo2, attn_out, tmp, nullptr, M_, D_, DFF_);
    ln_kernel<<<M_, 256, 0, stream>>>(tmp, g2, b2, out, nullptr);
}